// Round 8
// baseline (371.075 us; speedup 1.0000x reference)
//
#include <hip/hip_runtime.h>
#include <math.h>

// Problem constants (from reference setup_inputs)
#define NC 80            // NUM_CLASSES
constexpr int BS  = 16;      // batch
constexpr int NA  = 33600;   // anchors
constexpr int NG  = 64;      // gt boxes
constexpr int TPB = 256;
constexpr int NBLK = (NA + TPB - 1) / TPB;  // 132 blocks per batch
constexpr int NW   = TPB / 64;              // 4 waves per block
constexpr int NC4  = NC / 4;                // 20 float4 per score row

typedef float f32x4 __attribute__((ext_vector_type(4)));

// branchless insert of v into descending top-3 (t0 >= t1 >= t2): 6 VALU ops
__device__ __forceinline__ void ins3(float v, float& t0, float& t1, float& t2) {
  t2 = fmaxf(t2, fminf(v, t1));   // uses old t1
  t1 = fmaxf(t1, fminf(v, t0));   // uses old t0
  t0 = fmaxf(t0, v);
}

// 64-lane butterfly top3 merge
__device__ __forceinline__ void wave_top3(float& t0, float& t1, float& t2) {
  #pragma unroll
  for (int off = 32; off > 0; off >>= 1) {
    float u0 = __shfl_xor(t0, off, 64);
    float u1 = __shfl_xor(t1, off, 64);
    float u2 = __shfl_xor(t2, off, 64);
    ins3(u0, t0, t1, t2);
    ins3(u1, t0, t1, t2);
    ins3(u2, t0, t1, t2);
  }
}

// ---------------------------------------------------------------------------
// P1: the proven R5 structure (282.2 µs — best measured), bit-for-bit:
// prefetch pd -> stage GT in LDS -> barrier -> IoU loop (exact IEEE divide,
// every comparison bit-identical to numpy) -> per-anchor outputs ->
// wave-local inline one-hot emit (single-pass, shfl(own_cls,row), no
// barrier, nontemporal) -> wave max -> deferred top-3 behind the
// wave-uniform wmax<=0.3 gate -> blockTop writes.
// NEW (fused==1): last-block-done tail replaces the p3 kernel. Every block:
// __syncthreads (all waves' stores are vmcnt(0)-drained at the barrier) ->
// tid0 __threadfence (device-scope release; covers per-XCD L2
// non-coherence) -> atomicAdd(ctr[b]). The 132nd block per batch acquires
// and runs the p3 decision inline: reduce the batch's 528 per-wave maxima;
// common case exits; the never-taken fallback rewrites the batch using the
// GT tile still in this block's LDS (identical algorithm to the old p3).
// target_gt_idx is fallback-independent -> never rewritten.
// ---------------------------------------------------------------------------
__global__ __launch_bounds__(TPB) void p1_kernel(
    const float4* __restrict__ pd, const float4* __restrict__ gt,
    const int* __restrict__ glab, const int* __restrict__ gmask,
    float* __restrict__ outL, float4* __restrict__ outB,
    float* __restrict__ outS, float* __restrict__ outF,
    float* __restrict__ outI, float* __restrict__ blockTop,
    int* __restrict__ ctr, int fused)
{
  #pragma clang fp contract(off)
  const int b   = blockIdx.y;
  const int tid = threadIdx.x;

  __shared__ float4 sbox[NG];
  __shared__ float  sarea[NG];
  __shared__ int    slab[NG];
  __shared__ int    svalid[NG];
  // tail (last-block decision) shared state
  __shared__ int    sLast;
  __shared__ float  swm[NW];
  __shared__ float  sM;
  __shared__ float  swt[NW][3];
  __shared__ float  sres;
  __shared__ int    sfb;

  const int a0  = blockIdx.x * TPB;
  const int a   = a0 + tid;
  const bool inb = a < NA;
  const int lane = tid & 63, wid = tid >> 6;

  // ---- own pd box (issued before the barrier) ----
  float4 p = make_float4(0.f, 0.f, 0.f, 0.f);
  if (inb) p = pd[(long)b * NA + a];

  // ---- stage gt into LDS ----
  if (tid < NG) {
    int v = gmask[b * NG + tid];
    float4 g = gt[b * NG + tid];
    if (!v) g = make_float4(0.f, 0.f, 0.f, 0.f);  // zero-box => iou == 0
    sbox[tid]   = g;
    sarea[tid]  = (g.z - g.x) * (g.w - g.y);
    slab[tid]   = glab[b * NG + tid];
    svalid[tid] = v;
  }
  __syncthreads();

  float best = -1.f;
  int   bidx = 0;
  float a2 = 0.f;
  bool  maskv = false;
  int   blab  = 0;

  if (inb) {
    a2 = (p.z - p.x) * (p.w - p.y);
    #pragma unroll 8
    for (int g = 0; g < NG; ++g) {
      float4 gb = sbox[g];
      float iw = fminf(gb.z, p.z) - fmaxf(gb.x, p.x);
      float ih = fminf(gb.w, p.w) - fmaxf(gb.y, p.y);
      iw = fmaxf(iw, 0.f);
      ih = fmaxf(ih, 0.f);
      float inter = iw * ih;
      float den   = sarea[g] + a2 - inter + 1e-9f;
      float iou   = inter / den;                 // exact IEEE, matches np
      bidx = (iou > best) ? g : bidx;            // first-index tie-break
      best = fmaxf(best, iou);
    }
    bool fg = best > 0.3f;
    maskv = fg && (svalid[bidx] != 0);
    blab  = slab[bidx];
    long ga = (long)b * NA + a;
    outL[ga] = maskv ? (float)blab : 80.f;       // BG_IDX = 80
    float m = maskv ? 1.f : 0.f;
    float4 gb = sbox[bidx];
    outB[ga] = make_float4(gb.x * m, gb.y * m, gb.z * m, gb.w * m);
    outF[ga] = fg ? 1.f : 0.f;
    outI[ga] = (float)bidx;
  }

  // ---- wave-local one-hot emit: wave w owns rows [w*64, w*64+64) of this
  // block's score tile; each row's class comes from the owning lane via
  // shfl. No barrier, no LDS — stores issue as soon as this wave's IoU
  // loop retires, and waves drain independently. Coalesced 64x16B lines,
  // nontemporal (outS is never re-read on the hot path). ----
  const int nA    = min(TPB, NA - a0);
  const int wrow0 = wid * 64;                   // wave's first local row
  const int rows  = min(64, nA - wrow0);        // <=0 for fully-OOB waves
  const int own_cls = maskv ? blab : -1;        // -1 = background
  if (rows > 0) {
    f32x4* s4 = reinterpret_cast<f32x4*>(outS + ((long)b * NA + a0 + wrow0) * NC);
    const int cnt4 = rows * NC4;
    for (int i = lane; i < cnt4; i += 64) {
      int row = i / NC4;               // magic-mul div by 20
      int c0  = (i - row * NC4) * 4;   // starting class of this float4
      int cls = __shfl(own_cls, row, 64);
      f32x4 v;
      v.x = (cls == c0    ) ? 1.f : 0.f;
      v.y = (cls == c0 + 1) ? 1.f : 0.f;
      v.z = (cls == c0 + 2) ? 1.f : 0.f;
      v.w = (cls == c0 + 3) ? 1.f : 0.f;
      __builtin_nontemporal_store(v, s4 + i);
    }
  }

  // ---- per-wave max of best (cheap: 6 shfl + 6 fmax) ----
  float wmax = best;
  #pragma unroll
  for (int off = 32; off > 0; off >>= 1)
    wmax = fmaxf(wmax, __shfl_xor(wmax, off, 64));

  float* bt = blockTop + (((long)b * NBLK + blockIdx.x) * NW + wid) * 3;

  // ---- rare path: this wave cannot prove fg. Recompute ious with full
  // top-3 tracking and publish the triple's tail. Global need_fb implies
  // ALL waves land here, so the triples the decision consumer reads are
  // always freshly written. (OOB tail waves publish -inf tails and
  // wmax=-1 — both below any real iou >= 0, so the batch top-3, always
  // >= 0 with 33600 real anchors, is unaffected.) ----
  if (wmax <= 0.3f) {                            // wave-uniform branch
    float t0 = -INFINITY, t1 = -INFINITY, t2 = -INFINITY;
    if (inb) {
      #pragma unroll 4
      for (int g = 0; g < NG; ++g) {
        float4 gb = sbox[g];
        float iw = fminf(gb.z, p.z) - fmaxf(gb.x, p.x);
        float ih = fminf(gb.w, p.w) - fmaxf(gb.y, p.y);
        iw = fmaxf(iw, 0.f);
        ih = fmaxf(ih, 0.f);
        float inter = iw * ih;
        float den   = sarea[g] + a2 - inter + 1e-9f;
        float iou   = inter / den;
        ins3(iou, t0, t1, t2);
      }
    }
    wave_top3(t0, t1, t2);
    if (lane == 0) { bt[1] = t1; bt[2] = t2; }
  }
  // ---- unconditional per-wave max (slot 0; t0 == wmax on the slow path) ----
  if (lane == 0) bt[0] = wmax;

  // ======================= fused p3 tail (last-block-done) =======================
  if (!fused) return;              // uniform: falls back to the separate p3 kernel

  __syncthreads();                 // all waves' stores drained (vmcnt(0)) at barrier
  if (tid == 0) {
    __threadfence();               // device-scope release of this block's writes
    int old = atomicAdd(&ctr[b], 1);
    sLast = (old == NBLK - 1) ? 1 : 0;
  }
  __syncthreads();
  if (!sLast) return;              // 131 of 132 blocks exit here
  __threadfence();                 // acquire: other blocks' writes now visible

  // ---- fast decision: max over this batch's per-wave maxima (slot 0) ----
  float m = -INFINITY;
  for (int i = tid; i < NBLK * NW; i += TPB)
    m = fmaxf(m, blockTop[((long)b * NBLK * NW + i) * 3]);
  #pragma unroll
  for (int off = 32; off > 0; off >>= 1)
    m = fmaxf(m, __shfl_xor(m, off, 64));
  if (lane == 0) swm[wid] = m;
  __syncthreads();
  if (tid == 0) {
    float r = swm[0];
    #pragma unroll
    for (int w = 1; w < NW; ++w) r = fmaxf(r, swm[w]);
    sM = r;
  }
  __syncthreads();
  if (sM > 0.3f) return;           // common case: batch has fg -> uniform exit

  // ================= cold fallback (never taken on this data) =================
  int gv = (tid < NG) ? gmask[b * NG + tid] : 0;
  unsigned long long bal = __ballot(gv != 0);  // valid in wave 0

  float t0 = -INFINITY, t1 = -INFINITY, t2 = -INFINITY;
  for (int i = tid; i < NBLK * NW; i += TPB) {
    const float* btp = blockTop + ((long)b * NBLK * NW + i) * 3;
    ins3(btp[0], t0, t1, t2);
    ins3(btp[1], t0, t1, t2);
    ins3(btp[2], t0, t1, t2);
  }
  wave_top3(t0, t1, t2);
  if (lane == 0) { swt[wid][0] = t0; swt[wid][1] = t1; swt[wid][2] = t2; }
  __syncthreads();
  if (tid == 0) {
    float r0 = swt[0][0], r1 = swt[0][1], r2 = swt[0][2];
    #pragma unroll
    for (int w = 1; w < NW; ++w) {
      ins3(swt[w][0], r0, r1, r2);
      ins3(swt[w][1], r0, r1, r2);
      ins3(swt[w][2], r0, r1, r2);
    }
    sfb  = (!(r0 > 0.3f) && bal != 0ULL) ? 1 : 0;
    sres = r2;
  }
  __syncthreads();
  if (sfb == 0) return;            // uniform exit
  const float minio = sres;

  // grid-stride rewrite of the whole batch from this single block (cold).
  // sbox/sarea/slab/svalid are still resident in this block's LDS.
  for (int aa = tid; aa < NA; aa += TPB) {
    float4 pp  = pd[(long)b * NA + aa];
    float  pa2 = (pp.z - pp.x) * (pp.w - pp.y);
    float bb = -1.f;
    int   bi = 0;
    #pragma unroll 8
    for (int g = 0; g < NG; ++g) {
      float4 gb = sbox[g];
      float iw = fminf(gb.z, pp.z) - fmaxf(gb.x, pp.x);
      float ih = fminf(gb.w, pp.w) - fmaxf(gb.y, pp.y);
      iw = fmaxf(iw, 0.f);
      ih = fmaxf(ih, 0.f);
      float inter = iw * ih;
      float den   = sarea[g] + pa2 - inter + 1e-9f;
      float iou   = inter / den;
      bi = (iou > bb) ? g : bi;
      bb = fmaxf(bb, iou);
    }
    // fallback fg: max over valid of overlaps >= min_iou. With zero-boxes
    // and has_valid guaranteed here, max over all g == max over valid g.
    bool fg    = bb >= minio;
    bool mk    = fg && (svalid[bi] != 0);
    int  lb    = slab[bi];
    long ga = (long)b * NA + aa;
    outL[ga] = mk ? (float)lb : 80.f;
    float mm = mk ? 1.f : 0.f;
    float4 gb = sbox[bi];
    outB[ga] = make_float4(gb.x * mm, gb.y * mm, gb.z * mm, gb.w * mm);
    outF[ga] = fg ? 1.f : 0.f;
    if (mk) outS[ga * NC + lb] = 1.f;  // scores were all-zero for this batch
  }
}

// ---------------------------------------------------------------------------
// P3: standalone fallback kernel — used ONLY when ws_size lacks room for the
// counters (keeps the verified R5 two-kernel behavior as a safety net).
// ---------------------------------------------------------------------------
__global__ __launch_bounds__(TPB) void p3_kernel(
    const float4* __restrict__ pd, const float4* __restrict__ gt,
    const int* __restrict__ glab, const int* __restrict__ gmask,
    const float* __restrict__ blockTop,
    float* __restrict__ outL, float4* __restrict__ outB,
    float* __restrict__ outS, float* __restrict__ outF)
{
  #pragma clang fp contract(off)
  const int b   = blockIdx.x;
  const int tid = threadIdx.x;

  __shared__ float  swm[NW];
  __shared__ float  sM;
  __shared__ float  swt[NW][3];
  __shared__ float  sres;
  __shared__ int    sfb;
  __shared__ float4 sbox[NG];
  __shared__ float  sarea[NG];
  __shared__ int    slab[NG];
  __shared__ int    svalid[NG];

  float m = -INFINITY;
  for (int i = tid; i < NBLK * NW; i += TPB)
    m = fmaxf(m, blockTop[((long)b * NBLK * NW + i) * 3]);
  #pragma unroll
  for (int off = 32; off > 0; off >>= 1)
    m = fmaxf(m, __shfl_xor(m, off, 64));
  const int lane = tid & 63, wid = tid >> 6;
  if (lane == 0) swm[wid] = m;
  __syncthreads();
  if (tid == 0) {
    float r = swm[0];
    #pragma unroll
    for (int w = 1; w < NW; ++w) r = fmaxf(r, swm[w]);
    sM = r;
  }
  __syncthreads();
  if (sM > 0.3f) return;

  int gv = (tid < NG) ? gmask[b * NG + tid] : 0;
  unsigned long long bal = __ballot(gv != 0);

  float t0 = -INFINITY, t1 = -INFINITY, t2 = -INFINITY;
  for (int i = tid; i < NBLK * NW; i += TPB) {
    const float* bt = blockTop + ((long)b * NBLK * NW + i) * 3;
    ins3(bt[0], t0, t1, t2);
    ins3(bt[1], t0, t1, t2);
    ins3(bt[2], t0, t1, t2);
  }
  wave_top3(t0, t1, t2);
  if (lane == 0) { swt[wid][0] = t0; swt[wid][1] = t1; swt[wid][2] = t2; }
  __syncthreads();
  if (tid == 0) {
    float r0 = swt[0][0], r1 = swt[0][1], r2 = swt[0][2];
    #pragma unroll
    for (int w = 1; w < NW; ++w) {
      ins3(swt[w][0], r0, r1, r2);
      ins3(swt[w][1], r0, r1, r2);
      ins3(swt[w][2], r0, r1, r2);
    }
    sfb  = (!(r0 > 0.3f) && bal != 0ULL) ? 1 : 0;
    sres = r2;
  }
  if (tid < NG) {
    float4 g = gt[b * NG + tid];
    if (!gv) g = make_float4(0.f, 0.f, 0.f, 0.f);
    sbox[tid]   = g;
    sarea[tid]  = (g.z - g.x) * (g.w - g.y);
    slab[tid]   = glab[b * NG + tid];
    svalid[tid] = gv;
  }
  __syncthreads();
  if (sfb == 0) return;
  const float minio = sres;

  for (int a = tid; a < NA; a += TPB) {
    float4 p  = pd[(long)b * NA + a];
    float  a2 = (p.z - p.x) * (p.w - p.y);
    float best = -1.f;
    int   bidx = 0;
    #pragma unroll 8
    for (int g = 0; g < NG; ++g) {
      float4 gb = sbox[g];
      float iw = fminf(gb.z, p.z) - fmaxf(gb.x, p.x);
      float ih = fminf(gb.w, p.w) - fmaxf(gb.y, p.y);
      iw = fmaxf(iw, 0.f);
      ih = fmaxf(ih, 0.f);
      float inter = iw * ih;
      float den   = sarea[g] + a2 - inter + 1e-9f;
      float iou   = inter / den;
      bidx = (iou > best) ? g : bidx;
      best = fmaxf(best, iou);
    }
    bool fg    = best >= minio;
    bool maskv = fg && (svalid[bidx] != 0);
    int  blab  = slab[bidx];
    long ga = (long)b * NA + a;
    outL[ga] = maskv ? (float)blab : 80.f;
    float mm = maskv ? 1.f : 0.f;
    float4 gb = sbox[bidx];
    outB[ga] = make_float4(gb.x * mm, gb.y * mm, gb.z * mm, gb.w * mm);
    outF[ga] = fg ? 1.f : 0.f;
    if (maskv) outS[ga * NC + blab] = 1.f;
  }
}

// ---------------------------------------------------------------------------
// launch
// ---------------------------------------------------------------------------
extern "C" void kernel_launch(void* const* d_in, const int* in_sizes, int n_in,
                              void* d_out, int out_size, void* d_ws, size_t ws_size,
                              hipStream_t stream) {
  // inputs (setup_inputs order): 0 pd_scores (unused), 1 pd_bboxes,
  // 2 anc_points (unused), 3 gt_labels, 4 gt_bboxes, 5 mask_gt
  const float4* pd    = (const float4*)d_in[1];
  const int*    glab  = (const int*)d_in[3];
  const float4* gt    = (const float4*)d_in[4];
  const int*    gmask = (const int*)d_in[5];

  float* outf = (float*)d_out;
  // outputs concatenated flat in return order (all as float32):
  // target_labels [16,33600], target_bboxes [16,33600,4],
  // target_scores [16,33600,80], fg_mask [16,33600], target_gt_idx [16,33600]
  float*  outL = outf;
  float4* outB = (float4*)(outf + (long)BS * NA);
  float*  outS = outf + (long)BS * NA * 5;
  float*  outF = outf + (long)BS * NA * 5 + (long)BS * NA * NC;
  float*  outI = outF + (long)BS * NA;

  // workspace layout: blockTop (proven BS*NBLK*NW*3 floats = 101376 B) and,
  // IF ws_size has room, BS int counters for the fused last-block-done tail.
  float* blockTop = (float*)d_ws;
  const size_t btBytes = (size_t)BS * NBLK * NW * 3 * sizeof(float); // 101376
  const size_t ctrOff  = btBytes;                                    // 128-aligned
  const bool   fused   = ws_size >= ctrOff + BS * sizeof(int);
  int* ctr = (int*)((char*)d_ws + ctrOff);

  if (fused) hipMemsetAsync(ctr, 0, BS * sizeof(int), stream);

  dim3 grid(NBLK, BS);
  p1_kernel<<<grid, TPB, 0, stream>>>(pd, gt, glab, gmask,
                                      outL, outB, outS, outF, outI,
                                      blockTop, ctr, fused ? 1 : 0);
  if (!fused)
    p3_kernel<<<BS, TPB, 0, stream>>>(pd, gt, glab, gmask, blockTop,
                                      outL, outB, outS, outF);
}

// Round 9
// 283.055 us; speedup vs baseline: 1.3110x; 1.3110x over previous
//
#include <hip/hip_runtime.h>
#include <math.h>

// Problem constants (from reference setup_inputs)
#define NC 80            // NUM_CLASSES
constexpr int BS  = 16;      // batch
constexpr int NA  = 33600;   // anchors
constexpr int NG  = 64;      // gt boxes
constexpr int TPB = 256;
constexpr int NBLK = (NA + TPB - 1) / TPB;  // 132 blocks per batch
constexpr int NW   = TPB / 64;              // 4 waves per block
constexpr int NC4  = NC / 4;                // 20 float4 per score row

typedef float f32x4 __attribute__((ext_vector_type(4)));

// branchless insert of v into descending top-3 (t0 >= t1 >= t2): 6 VALU ops
__device__ __forceinline__ void ins3(float v, float& t0, float& t1, float& t2) {
  t2 = fmaxf(t2, fminf(v, t1));   // uses old t1
  t1 = fmaxf(t1, fminf(v, t0));   // uses old t0
  t0 = fmaxf(t0, v);
}

// 64-lane butterfly top3 merge
__device__ __forceinline__ void wave_top3(float& t0, float& t1, float& t2) {
  #pragma unroll
  for (int off = 32; off > 0; off >>= 1) {
    float u0 = __shfl_xor(t0, off, 64);
    float u1 = __shfl_xor(t1, off, 64);
    float u2 = __shfl_xor(t2, off, 64);
    ins3(u0, t0, t1, t2);
    ins3(u1, t0, t1, t2);
    ins3(u2, t0, t1, t2);
  }
}

// ---------------------------------------------------------------------------
// P1: the proven best structure (282.2 µs, Round-5 measurement), reverted
// bit-for-bit after R8's fused-tail regression (device-scope __threadfence
// per block => L2 writeback storm => p1 at 1.4 TB/s). Flow: prefetch pd ->
// stage GT in LDS -> barrier -> IoU loop (exact IEEE divide: every
// comparison bit-identical to numpy) -> per-anchor outputs -> wave-local
// single-pass inline one-hot emit (shfl(own_cls,row), no second barrier,
// waves retire independently) -> wave max -> deferred top-3 behind the
// wave-uniform wmax<=0.3 gate -> blockTop writes.
// ONE A/B change vs the 282.2 baseline: the emit uses REGULAR stores
// instead of nontemporal — full-line wave stores (1 KB/instr, no RFO) let
// L2 + memory-side Infinity Cache absorb the 183 MB burst instead of
// streaming to HBM. If p1's FETCH_SIZE inflates ~180 MB, RFO appeared and
// the next round reverts to NT.
// Invalid GT boxes are zeroed in LDS so their IoU is exactly 0.0.
// ---------------------------------------------------------------------------
__global__ __launch_bounds__(TPB) void p1_kernel(
    const float4* __restrict__ pd, const float4* __restrict__ gt,
    const int* __restrict__ glab, const int* __restrict__ gmask,
    float* __restrict__ outL, float4* __restrict__ outB,
    float* __restrict__ outS, float* __restrict__ outF,
    float* __restrict__ outI, float* __restrict__ blockTop)
{
  #pragma clang fp contract(off)
  const int b   = blockIdx.y;
  const int tid = threadIdx.x;

  __shared__ float4 sbox[NG];
  __shared__ float  sarea[NG];
  __shared__ int    slab[NG];
  __shared__ int    svalid[NG];

  const int a0  = blockIdx.x * TPB;
  const int a   = a0 + tid;
  const bool inb = a < NA;
  const int lane = tid & 63, wid = tid >> 6;

  // ---- own pd box (issued before the barrier) ----
  float4 p = make_float4(0.f, 0.f, 0.f, 0.f);
  if (inb) p = pd[(long)b * NA + a];

  // ---- stage gt into LDS ----
  if (tid < NG) {
    int v = gmask[b * NG + tid];
    float4 g = gt[b * NG + tid];
    if (!v) g = make_float4(0.f, 0.f, 0.f, 0.f);  // zero-box => iou == 0
    sbox[tid]   = g;
    sarea[tid]  = (g.z - g.x) * (g.w - g.y);
    slab[tid]   = glab[b * NG + tid];
    svalid[tid] = v;
  }
  __syncthreads();   // the ONLY barrier

  float best = -1.f;
  int   bidx = 0;
  float a2 = 0.f;
  bool  maskv = false;
  int   blab  = 0;

  if (inb) {
    a2 = (p.z - p.x) * (p.w - p.y);
    #pragma unroll 8
    for (int g = 0; g < NG; ++g) {
      float4 gb = sbox[g];
      float iw = fminf(gb.z, p.z) - fmaxf(gb.x, p.x);
      float ih = fminf(gb.w, p.w) - fmaxf(gb.y, p.y);
      iw = fmaxf(iw, 0.f);
      ih = fmaxf(ih, 0.f);
      float inter = iw * ih;
      float den   = sarea[g] + a2 - inter + 1e-9f;
      float iou   = inter / den;                 // exact IEEE, matches np
      bidx = (iou > best) ? g : bidx;            // first-index tie-break
      best = fmaxf(best, iou);
    }
    bool fg = best > 0.3f;
    maskv = fg && (svalid[bidx] != 0);
    blab  = slab[bidx];
    long ga = (long)b * NA + a;
    outL[ga] = maskv ? (float)blab : 80.f;       // BG_IDX = 80
    float m = maskv ? 1.f : 0.f;
    float4 gb = sbox[bidx];
    outB[ga] = make_float4(gb.x * m, gb.y * m, gb.z * m, gb.w * m);
    outF[ga] = fg ? 1.f : 0.f;
    outI[ga] = (float)bidx;
  }

  // ---- wave-local one-hot emit: wave w owns rows [w*64, w*64+64) of this
  // block's score tile; each row's class comes from the owning lane via
  // shfl. No barrier, no LDS — stores issue as soon as this wave's IoU
  // loop retires, and waves drain independently. Coalesced 64x16B lines
  // (full cache lines per instruction -> no RFO), REGULAR stores so
  // L2/Infinity-Cache absorbs the burst (A/B vs NT, see header). ----
  const int nA    = min(TPB, NA - a0);
  const int wrow0 = wid * 64;                   // wave's first local row
  const int rows  = min(64, nA - wrow0);        // <=0 for fully-OOB waves
  const int own_cls = maskv ? blab : -1;        // -1 = background
  if (rows > 0) {
    f32x4* s4 = reinterpret_cast<f32x4*>(outS + ((long)b * NA + a0 + wrow0) * NC);
    const int cnt4 = rows * NC4;
    for (int i = lane; i < cnt4; i += 64) {
      int row = i / NC4;               // magic-mul div by 20
      int c0  = (i - row * NC4) * 4;   // starting class of this float4
      int cls = __shfl(own_cls, row, 64);
      f32x4 v;
      v.x = (cls == c0    ) ? 1.f : 0.f;
      v.y = (cls == c0 + 1) ? 1.f : 0.f;
      v.z = (cls == c0 + 2) ? 1.f : 0.f;
      v.w = (cls == c0 + 3) ? 1.f : 0.f;
      s4[i] = v;                       // regular store (A/B change vs NT)
    }
  }

  // ---- per-wave max of best (cheap: 6 shfl + 6 fmax) ----
  float wmax = best;
  #pragma unroll
  for (int off = 32; off > 0; off >>= 1)
    wmax = fmaxf(wmax, __shfl_xor(wmax, off, 64));

  float* bt = blockTop + (((long)b * NBLK + blockIdx.x) * NW + wid) * 3;

  // ---- rare path: this wave cannot prove fg. Recompute ious with full
  // top-3 tracking and publish the triple's tail. Global need_fb implies
  // ALL waves land here, so the triples the slow consumer reads are always
  // freshly written. (OOB tail waves publish -inf tails and wmax=-1 — both
  // below any real iou >= 0, so the batch top-3, always >= 0 with 33600
  // real anchors, is unaffected.) ----
  if (wmax <= 0.3f) {                            // wave-uniform branch
    float t0 = -INFINITY, t1 = -INFINITY, t2 = -INFINITY;
    if (inb) {
      #pragma unroll 4
      for (int g = 0; g < NG; ++g) {
        float4 gb = sbox[g];
        float iw = fminf(gb.z, p.z) - fmaxf(gb.x, p.x);
        float ih = fminf(gb.w, p.w) - fmaxf(gb.y, p.y);
        iw = fmaxf(iw, 0.f);
        ih = fmaxf(ih, 0.f);
        float inter = iw * ih;
        float den   = sarea[g] + a2 - inter + 1e-9f;
        float iou   = inter / den;
        ins3(iou, t0, t1, t2);
      }
    }
    wave_top3(t0, t1, t2);
    if (lane == 0) { bt[1] = t1; bt[2] = t2; }
  }
  // ---- unconditional per-wave max (slot 0; t0 == wmax on the slow path) ----
  if (lane == 0) bt[0] = wmax;
}

// ---------------------------------------------------------------------------
// P3: fallback fixup, ONE BLOCK PER BATCH (grid = BS). Fast path: reduce
// max over this batch's per-wave maxima (528 stride-3 floats, L2-hot) and
// exit uniformly. Cold path (never taken on this data, kept correct):
// ballot over gmask, full top-3 reduce of blockTop triples for min_iou,
// then a grid-stride loop over all NA anchors doing the rewrite + one-hot
// scatter from this single block. need_fb implies P1 wrote the batch
// entirely as background (scores all zero), so only rewrites are needed;
// target_gt_idx is fallback-independent -> untouched.
// ---------------------------------------------------------------------------
__global__ __launch_bounds__(TPB) void p3_kernel(
    const float4* __restrict__ pd, const float4* __restrict__ gt,
    const int* __restrict__ glab, const int* __restrict__ gmask,
    const float* __restrict__ blockTop,
    float* __restrict__ outL, float4* __restrict__ outB,
    float* __restrict__ outS, float* __restrict__ outF)
{
  #pragma clang fp contract(off)
  const int b   = blockIdx.x;
  const int tid = threadIdx.x;

  __shared__ float  swm[NW];
  __shared__ float  sM;
  __shared__ float  swt[NW][3];
  __shared__ float  sres;
  __shared__ int    sfb;
  __shared__ float4 sbox[NG];
  __shared__ float  sarea[NG];
  __shared__ int    slab[NG];
  __shared__ int    svalid[NG];

  // ---- fast decision: max over this batch's per-wave maxima (slot 0) ----
  float m = -INFINITY;
  for (int i = tid; i < NBLK * NW; i += TPB)
    m = fmaxf(m, blockTop[((long)b * NBLK * NW + i) * 3]);
  #pragma unroll
  for (int off = 32; off > 0; off >>= 1)
    m = fmaxf(m, __shfl_xor(m, off, 64));
  const int lane = tid & 63, wid = tid >> 6;
  if (lane == 0) swm[wid] = m;
  __syncthreads();
  if (tid == 0) {
    float r = swm[0];
    #pragma unroll
    for (int w = 1; w < NW; ++w) r = fmaxf(r, swm[w]);
    sM = r;
  }
  __syncthreads();
  if (sM > 0.3f) return;       // common case: batch has fg -> uniform exit

  // ================= slow path (cold, correctness only) =================
  int gv = (tid < NG) ? gmask[b * NG + tid] : 0;
  unsigned long long bal = __ballot(gv != 0);  // valid in wave 0

  // reduce batch's per-wave top3 triples (all freshly written: global
  // fallback implies every p1 wave took the rare path)
  float t0 = -INFINITY, t1 = -INFINITY, t2 = -INFINITY;
  for (int i = tid; i < NBLK * NW; i += TPB) {
    const float* bt = blockTop + ((long)b * NBLK * NW + i) * 3;
    ins3(bt[0], t0, t1, t2);
    ins3(bt[1], t0, t1, t2);
    ins3(bt[2], t0, t1, t2);
  }
  wave_top3(t0, t1, t2);
  if (lane == 0) { swt[wid][0] = t0; swt[wid][1] = t1; swt[wid][2] = t2; }
  __syncthreads();
  if (tid == 0) {
    float r0 = swt[0][0], r1 = swt[0][1], r2 = swt[0][2];
    #pragma unroll
    for (int w = 1; w < NW; ++w) {
      ins3(swt[w][0], r0, r1, r2);
      ins3(swt[w][1], r0, r1, r2);
      ins3(swt[w][2], r0, r1, r2);
    }
    sfb  = (!(r0 > 0.3f) && bal != 0ULL) ? 1 : 0;
    sres = r2;
  }
  // stage gt into LDS (overlaps the decision barrier)
  if (tid < NG) {
    float4 g = gt[b * NG + tid];
    if (!gv) g = make_float4(0.f, 0.f, 0.f, 0.f);
    sbox[tid]   = g;
    sarea[tid]  = (g.z - g.x) * (g.w - g.y);
    slab[tid]   = glab[b * NG + tid];
    svalid[tid] = gv;
  }
  __syncthreads();
  if (sfb == 0) return;        // uniform exit (no barriers after this)
  const float minio = sres;

  // grid-stride rewrite of the whole batch from this single block (cold)
  for (int a = tid; a < NA; a += TPB) {
    float4 p  = pd[(long)b * NA + a];
    float  a2 = (p.z - p.x) * (p.w - p.y);
    float best = -1.f;
    int   bidx = 0;
    #pragma unroll 8
    for (int g = 0; g < NG; ++g) {
      float4 gb = sbox[g];
      float iw = fminf(gb.z, p.z) - fmaxf(gb.x, p.x);
      float ih = fminf(gb.w, p.w) - fmaxf(gb.y, p.y);
      iw = fmaxf(iw, 0.f);
      ih = fmaxf(ih, 0.f);
      float inter = iw * ih;
      float den   = sarea[g] + a2 - inter + 1e-9f;
      float iou   = inter / den;
      bidx = (iou > best) ? g : bidx;
      best = fmaxf(best, iou);
    }
    // fallback fg: max over valid of overlaps >= min_iou. With zero-boxes
    // and has_valid guaranteed here, max over all g == max over valid g.
    bool fg    = best >= minio;
    bool maskv = fg && (svalid[bidx] != 0);
    int  blab  = slab[bidx];
    long ga = (long)b * NA + a;
    outL[ga] = maskv ? (float)blab : 80.f;
    float mm = maskv ? 1.f : 0.f;
    float4 gb = sbox[bidx];
    outB[ga] = make_float4(gb.x * mm, gb.y * mm, gb.z * mm, gb.w * mm);
    outF[ga] = fg ? 1.f : 0.f;
    if (maskv) outS[ga * NC + blab] = 1.f;  // scores were all-zero here
  }
}

// ---------------------------------------------------------------------------
// launch
// ---------------------------------------------------------------------------
extern "C" void kernel_launch(void* const* d_in, const int* in_sizes, int n_in,
                              void* d_out, int out_size, void* d_ws, size_t ws_size,
                              hipStream_t stream) {
  // inputs (setup_inputs order): 0 pd_scores (unused), 1 pd_bboxes,
  // 2 anc_points (unused), 3 gt_labels, 4 gt_bboxes, 5 mask_gt
  const float4* pd    = (const float4*)d_in[1];
  const int*    glab  = (const int*)d_in[3];
  const float4* gt    = (const float4*)d_in[4];
  const int*    gmask = (const int*)d_in[5];

  float* outf = (float*)d_out;
  // outputs concatenated flat in return order (all as float32):
  // target_labels [16,33600], target_bboxes [16,33600,4],
  // target_scores [16,33600,80], fg_mask [16,33600], target_gt_idx [16,33600]
  float*  outL = outf;
  float4* outB = (float4*)(outf + (long)BS * NA);
  float*  outS = outf + (long)BS * NA * 5;
  float*  outF = outf + (long)BS * NA * 5 + (long)BS * NA * NC;
  float*  outI = outF + (long)BS * NA;

  // workspace: per-wave {max, top3-tail} triples — exactly the proven
  // BS*NBLK*NW*3 floats (~101 KB), no growth vs the verified baseline.
  float* blockTop = (float*)d_ws;

  dim3 grid(NBLK, BS);
  p1_kernel<<<grid, TPB, 0, stream>>>(pd, gt, glab, gmask,
                                      outL, outB, outS, outF, outI, blockTop);
  p3_kernel<<<BS, TPB, 0, stream>>>(pd, gt, glab, gmask, blockTop,
                                    outL, outB, outS, outF);
}